// Round 14
// baseline (159.532 us; speedup 1.0000x reference)
//
#include <hip/hip_runtime.h>
#include <math.h>

#define DIM   128
#define NC_   50000
#define NE_   100000
#define T_    800000
#define NTILE_E ((NE_ + 63) / 64)   // 1563
#define NTILE_C ((NC_ + 63) / 64)   // 782
#define NSTART  ((T_ + 1 + 255) / 256)

typedef __attribute__((ext_vector_type(8))) _Float16 f16x8;
typedef __attribute__((ext_vector_type(2))) _Float16 f16x2;
typedef __attribute__((ext_vector_type(4))) float f32x4;

__device__ __forceinline__ float sigmoidf_(float x) {
    return 1.f / (1.f + __expf(-x));
}

__device__ __forceinline__ float dot2f(f16x2 a, f16x2 b, float c) {
#if defined(__has_builtin) && __has_builtin(__builtin_amdgcn_fdot2)
    return __builtin_amdgcn_fdot2(a, b, c, false);
#else
    return c + (float)a[0] * (float)b[0] + (float)a[1] * (float)b[1];
#endif
}

// ---- K0 (merged prep): one launch, block-range split, all parts independent.
// blocks [0,8)   : pack W_e  -> packWe   (f16 B-fragment layout)
// blocks [8,16)  : pack W_c  -> packWc
// blocks [16,24) : pack W_g  -> packWg
// blocks [24,32) : packWtt[frag(k,n)] = f16( dot(W_t2v[k,:], W_t[:,n]) )  (inline matmul)
// block  32      : b_tt = b_t2v @ W_t + b_t
// blocks [33, 33+NSTART): segment start offsets
__global__ __launch_bounds__(256)
void k_prep(const float* __restrict__ W_e, const float* __restrict__ W_c,
            const float* __restrict__ W_g, const float* __restrict__ W_t2v,
            const float* __restrict__ W_t, const float* __restrict__ b_t2v,
            const float* __restrict__ b_t, const int* __restrict__ seg,
            _Float16* __restrict__ packWe, _Float16* __restrict__ packWc,
            _Float16* __restrict__ packWg, _Float16* __restrict__ packWtt,
            float* __restrict__ b_tt, int* __restrict__ start) {
    const int b = blockIdx.x;
    const int tid = threadIdx.x;

    if (b < 24) {
        // ---- pack: 8 blocks per matrix, 4 sub-tiles (64 lanes each) per block
        const float* src = (b < 8) ? W_e : (b < 16) ? W_c : W_g;
        _Float16* dst    = (b < 8) ? packWe : (b < 16) ? packWc : packWg;
        const int bb   = (b & 7) * 4 + (tid >> 6);   // 0..31
        const int lane = tid & 63;
        const int nt = bb >> 2, kb = bb & 3;
        const int n  = nt * 16 + (lane & 15);
        const int k0 = kb * 32 + 8 * (lane >> 4);
        const size_t off = ((size_t)(nt * 4 + kb) * 64 + lane) * 8;
        #pragma unroll
        for (int e = 0; e < 8; ++e)
            dst[off + e] = (_Float16)src[(size_t)(k0 + e) * DIM + n];
    } else if (b < 32) {
        // ---- packWtt: block handles nt = b-24; W_t 16-col panel staged in LDS
        __shared__ float ldsWt[DIM * 16];
        const int nt = b - 24;
        for (int idx = tid; idx < DIM * 16; idx += 256) {
            const int row = idx >> 4, col = idx & 15;
            ldsWt[idx] = W_t[(size_t)row * DIM + nt * 16 + col];
        }
        __syncthreads();
        const int kb   = tid >> 6;       // 0..3
        const int lane = tid & 63;
        const int nc   = lane & 15;
        const int k0   = kb * 32 + 8 * (lane >> 4);
        const size_t off = ((size_t)(nt * 4 + kb) * 64 + lane) * 8;
        #pragma unroll
        for (int e = 0; e < 8; ++e) {
            const int k = k0 + e;
            float acc = 0.f;
            #pragma unroll 4
            for (int m = 0; m < DIM; ++m)
                acc = fmaf(W_t2v[(size_t)k * DIM + m], ldsWt[m * 16 + nc], acc);
            packWtt[off + e] = (_Float16)acc;
        }
    } else if (b == 32) {
        // ---- b_tt
        const int j = tid;
        if (j < DIM) {
            float acc = b_t[j];
            for (int k = 0; k < DIM; ++k)
                acc = fmaf(b_t2v[k], W_t[(size_t)k * DIM + j], acc);
            b_tt[j] = acc;
        }
    } else {
        // ---- segment start offsets
        const int t = (b - 33) * 256 + tid;
        if (t > T_) return;
        if (t < T_) {
            int s  = seg[t];
            int sp = (t > 0) ? seg[t - 1] : -1;
            for (int c = sp + 1; c <= s; ++c) start[c] = t;
        } else {
            int sp = seg[T_ - 1];
            for (int c = sp + 1; c <= NC_; ++c) start[c] = T_;
        }
    }
}

__device__ __forceinline__ void split8h(const float* xs, f16x8* hi, f16x8* lo) {
    #pragma unroll
    for (int e = 0; e < 8; ++e) {
        _Float16 h = (_Float16)xs[e];
        (*hi)[e] = h;
        (*lo)[e] = (_Float16)(xs[e] - (float)h);
    }
}

__device__ __forceinline__ void stage_lds(_Float16* lds, const _Float16* __restrict__ g) {
    const int tid = threadIdx.x;
    #pragma unroll
    for (int i = 0; i < 8; ++i)
        ((uint4*)lds)[tid + i * 256] = ((const uint4*)g)[tid + i * 256];
}

__device__ __forceinline__ void mfma2(f16x8 ahi, f16x8 alo, const _Float16* lds_bp,
                                      f32x4* acc) {
    f16x8 b = *(const f16x8*)lds_bp;
    *acc = __builtin_amdgcn_mfma_f32_16x16x32_f16(ahi, b, *acc, 0, 0, 0);
    *acc = __builtin_amdgcn_mfma_f32_16x16x32_f16(alo, b, *acc, 0, 0, 0);
}

#define TSTRIDE 136   // padded f16 row stride for the LDS transpose buffer

// ---- K1 (merged): blocks [0,NTILE_E) edge path; [NTILE_E, +NTILE_C) code path.
// Edge: u16[e] = f16((H_e@We + be) * sigmoid(trig@W_tt + b_tt)); He16 = f16(H_e).
// Code: pc16[c] = f16(H_c@W_c + bc). Both use LDS-transposed coalesced epilogue.
__global__ __launch_bounds__(256)
void k_main(const float* __restrict__ H_e, const float* __restrict__ ts,
            const _Float16* __restrict__ packWe, const _Float16* __restrict__ packWtt,
            const _Float16* __restrict__ packWc,
            const float* __restrict__ be_lin, const float* __restrict__ b_e,
            const float* __restrict__ b_tt,
            const float* __restrict__ bc_lin, const float* __restrict__ b_c,
            const float* __restrict__ omega, const float* __restrict__ H_c,
            _Float16* __restrict__ u16, _Float16* __restrict__ He16,
            _Float16* __restrict__ pc16) {
    __shared__ __align__(16) _Float16 ldsW[16384];   // 32KB; reused as transpose buf
    const int tid  = threadIdx.x;
    const int lane = tid & 63;
    const int q    = lane & 15, g = lane >> 4;
    const int wv   = tid >> 6;

    if (blockIdx.x < NTILE_E) {
        // ================= edge path =================
        const int tile = blockIdx.x;
        const int brow = tile * 64 + wv * 16;
        const int arow = brow + q;
        const bool valid = arow < NE_;
        const float* ap = H_e + (size_t)(valid ? arow : 0) * DIM;
        const float te  = valid ? ts[arow] : 0.f;

        stage_lds(ldsW, packWe);

        f32x4 accU[8], accG[8];
        #pragma unroll
        for (int i = 0; i < 8; ++i) {
            accU[i] = (f32x4){0.f, 0.f, 0.f, 0.f};
            accG[i] = (f32x4){0.f, 0.f, 0.f, 0.f};
        }
        __syncthreads();

        // ---- GEMM U: H_e row @ We
        #pragma unroll
        for (int kb = 0; kb < 4; ++kb) {
            const int k0 = kb * 32 + 8 * g;
            float xs[8];
            if (valid) {
                float4 x0 = *(const float4*)(ap + k0);
                float4 x1 = *(const float4*)(ap + k0 + 4);
                xs[0]=x0.x; xs[1]=x0.y; xs[2]=x0.z; xs[3]=x0.w;
                xs[4]=x1.x; xs[5]=x1.y; xs[6]=x1.z; xs[7]=x1.w;
            } else {
                #pragma unroll
                for (int e = 0; e < 8; ++e) xs[e] = 0.f;
            }
            f16x8 ahi, alo;
            split8h(xs, &ahi, &alo);
            if (valid) *(f16x8*)&He16[(size_t)arow * DIM + k0] = ahi;  // 16B coalesced
            #pragma unroll
            for (int nt = 0; nt < 8; ++nt)
                mfma2(ahi, alo, &ldsW[((nt * 4 + kb) * 64 + lane) * 8], &accU[nt]);
        }

        __syncthreads();
        stage_lds(ldsW, packWtt);
        __syncthreads();

        // ---- GEMM G: trig(e) @ Wtt
        #pragma unroll
        for (int kb = 0; kb < 4; ++kb) {
            const int k0 = kb * 32 + 8 * g;
            float ys[8];
            #pragma unroll
            for (int e = 0; e < 8; ++e) {
                const int k = k0 + e;
                float x = te * omega[k & 63];
                float s, c;
                __sincosf(x, &s, &c);
                ys[e] = (k < 64) ? c : s;
            }
            f16x8 thi, tlo;
            split8h(ys, &thi, &tlo);
            #pragma unroll
            for (int nt = 0; nt < 8; ++nt)
                mfma2(thi, tlo, &ldsW[((nt * 4 + kb) * 64 + lane) * 8], &accG[nt]);
        }

        // ---- epilogue: u -> LDS transpose -> coalesced 64B stores
        __syncthreads();    // all Wtt reads done; ldsW reusable
        #pragma unroll
        for (int nt = 0; nt < 8; ++nt) {
            const int col = nt * 16 + q;
            const float bu = be_lin[col] + b_e[col];
            const float bg = b_tt[col];
            #pragma unroll
            for (int reg = 0; reg < 4; ++reg) {
                float val = (accU[nt][reg] + bu) * sigmoidf_(accG[nt][reg] + bg);
                ldsW[(wv * 16 + 4 * g + reg) * TSTRIDE + col] = (_Float16)val;
            }
        }
        __syncthreads();
        {
            const int row = tid >> 2;           // 0..63
            const int c0  = (tid & 3) * 32;     // 0,32,64,96
            const int er  = tile * 64 + row;
            if (er < NE_) {
                const _Float16* sp = &ldsW[row * TSTRIDE + c0];
                uint4* dst = (uint4*)&u16[(size_t)er * DIM + c0];
                dst[0] = *(const uint4*)(sp + 0);
                dst[1] = *(const uint4*)(sp + 8);
                dst[2] = *(const uint4*)(sp + 16);
                dst[3] = *(const uint4*)(sp + 24);
            }
        }
    } else {
        // ================= code path =================
        const int tile = blockIdx.x - NTILE_E;
        const int brow = tile * 64 + wv * 16;
        const int arow = brow + q;
        const bool valid = arow < NC_;
        const float* ap = H_c + (size_t)(valid ? arow : 0) * DIM;

        stage_lds(ldsW, packWc);

        f32x4 acc[8];
        #pragma unroll
        for (int i = 0; i < 8; ++i) acc[i] = (f32x4){0.f, 0.f, 0.f, 0.f};
        __syncthreads();

        #pragma unroll
        for (int kb = 0; kb < 4; ++kb) {
            const int k0 = kb * 32 + 8 * g;
            float xs[8];
            if (valid) {
                float4 x0 = *(const float4*)(ap + k0);
                float4 x1 = *(const float4*)(ap + k0 + 4);
                xs[0]=x0.x; xs[1]=x0.y; xs[2]=x0.z; xs[3]=x0.w;
                xs[4]=x1.x; xs[5]=x1.y; xs[6]=x1.z; xs[7]=x1.w;
            } else {
                #pragma unroll
                for (int e = 0; e < 8; ++e) xs[e] = 0.f;
            }
            f16x8 ahi, alo;
            split8h(xs, &ahi, &alo);
            #pragma unroll
            for (int nt = 0; nt < 8; ++nt)
                mfma2(ahi, alo, &ldsW[((nt * 4 + kb) * 64 + lane) * 8], &acc[nt]);
        }

        __syncthreads();    // all Wc reads done; ldsW reusable
        #pragma unroll
        for (int nt = 0; nt < 8; ++nt) {
            const int col = nt * 16 + q;
            const float bc = bc_lin[col] + b_c[col];
            #pragma unroll
            for (int reg = 0; reg < 4; ++reg)
                ldsW[(wv * 16 + 4 * g + reg) * TSTRIDE + col] = (_Float16)(acc[nt][reg] + bc);
        }
        __syncthreads();
        {
            const int row = tid >> 2;
            const int c0  = (tid & 3) * 32;
            const int cr  = tile * 64 + row;
            if (cr < NC_) {
                const _Float16* sp = &ldsW[row * TSTRIDE + c0];
                uint4* dst = (uint4*)&pc16[(size_t)cr * DIM + c0];
                dst[0] = *(const uint4*)(sp + 0);
                dst[1] = *(const uint4*)(sp + 8);
                dst[2] = *(const uint4*)(sp + 16);
                dst[3] = *(const uint4*)(sp + 24);
            }
        }
    }
}

// ---- K3: fused segment softmax + aggregation (f16 gathers, fdot2). R10-proven.
__global__ __launch_bounds__(256)
void k_seg(const _Float16* __restrict__ u16, _Float16* __restrict__ pc16,
           const _Float16* __restrict__ He16, const int* __restrict__ edge_ids,
           const int* __restrict__ start) {
    const int lane = threadIdx.x & 63;
    const int c = blockIdx.x * 4 + (threadIdx.x >> 6);
    if (c >= NC_) return;
    const int lo = start[c], hi = start[c + 1];
    const int g = lane >> 3;     // group 0..7
    const int q = lane & 7;      // lane in group
    const int j0 = q * 16;       // 16 dims owned by this lane

    union { uint4 r[2]; f16x2 h2[8]; } pcu;
    pcu.r[0] = *(const uint4*)&pc16[(size_t)c * DIM + j0];
    pcu.r[1] = *(const uint4*)&pc16[(size_t)c * DIM + j0 + 8];

    float M = -INFINITY, S = 0.f;
    float acc[16];
    #pragma unroll
    for (int i = 0; i < 16; ++i) acc[i] = 0.f;

    for (int base = lo; base < hi; base += 64) {
        const int n = min(64, hi - base);
        const int eid = (base + lane < hi) ? edge_ids[base + lane] : 0;
        const int niter = (n + 7) >> 3;
        float msc = -INFINITY;

        for (int jj = 0; jj < niter; ++jj) {
            const int s = 8 * jj + g;
            const int e = __shfl(eid, s);
            float p = 0.f;
            if (s < n) {
                union { uint4 r[2]; f16x2 h2[8]; } uu;
                const _Float16* up = &u16[(size_t)e * DIM + j0];
                uu.r[0] = *(const uint4*)up;
                uu.r[1] = *(const uint4*)(up + 8);
                #pragma unroll
                for (int i = 0; i < 8; ++i) p = dot2f(uu.h2[i], pcu.h2[i], p);
            }
            p += __shfl_xor(p, 1);
            p += __shfl_xor(p, 2);
            p += __shfl_xor(p, 4);
            if (q == jj && s < n) msc = p;
        }

        float cm = msc;
        #pragma unroll
        for (int off = 32; off; off >>= 1) cm = fmaxf(cm, __shfl_xor(cm, off));
        const float nM = fmaxf(M, cm);
        const float scale = __expf(M - nM);
        const float pi = __expf(msc - nM);
        float ss = pi;
        #pragma unroll
        for (int off = 32; off; off >>= 1) ss += __shfl_xor(ss, off);
        S = S * scale + ss;
        #pragma unroll
        for (int i = 0; i < 16; ++i) acc[i] *= scale;
        M = nM;

        for (int jj = 0; jj < niter; ++jj) {
            const int s = 8 * jj + g;
            const int e = __shfl(eid, s);
            const float p = __shfl(pi, 8 * g + jj);
            if (s < n) {
                union { uint4 r[2]; f16x8 h8[2]; } hh;
                const _Float16* hp = &He16[(size_t)e * DIM + j0];
                hh.r[0] = *(const uint4*)hp;
                hh.r[1] = *(const uint4*)(hp + 8);
                #pragma unroll
                for (int i = 0; i < 8; ++i) {
                    acc[i]     = fmaf(p, (float)hh.h8[0][i], acc[i]);
                    acc[8 + i] = fmaf(p, (float)hh.h8[1][i], acc[8 + i]);
                }
            }
        }
    }

    #pragma unroll
    for (int off = 8; off <= 32; off <<= 1) {
        #pragma unroll
        for (int i = 0; i < 16; ++i) acc[i] += __shfl_xor(acc[i], off);
    }

    if (g == 0) {
        const float inv = (hi > lo) ? 1.f / fmaxf(S, 1e-30f) : 0.f;
        union { uint4 r[2]; _Float16 h[16]; } o;
        #pragma unroll
        for (int i = 0; i < 16; ++i) o.h[i] = (_Float16)(acc[i] * inv);
        *(uint4*)&pc16[(size_t)c * DIM + j0]     = o.r[0];
        *(uint4*)&pc16[(size_t)c * DIM + j0 + 8] = o.r[1];
    }
}

// ---- K5: out[c] = has_edge ? 0.5*(v16@W_g + b_g) + 0.5*H_c : H_c
__global__ __launch_bounds__(256)
void k_out(const _Float16* __restrict__ v16, const _Float16* __restrict__ packWg,
           const float* __restrict__ b_g, const float* __restrict__ H_c,
           const int* __restrict__ start, float* __restrict__ out) {
    __shared__ __align__(16) _Float16 ldsW[16384];
    const int tid  = threadIdx.x;
    const int lane = tid & 63;
    const int q    = lane & 15, g = lane >> 4;
    const int brow = blockIdx.x * 64 + (tid >> 6) * 16;
    const int arow = brow + q;
    const bool valid = arow < NC_;
    const _Float16* ap = v16 + (size_t)(valid ? arow : 0) * DIM;

    stage_lds(ldsW, packWg);

    f32x4 acc[8];
    #pragma unroll
    for (int i = 0; i < 8; ++i) acc[i] = (f32x4){0.f, 0.f, 0.f, 0.f};
    __syncthreads();

    #pragma unroll
    for (int kb = 0; kb < 4; ++kb) {
        const int k0 = kb * 32 + 8 * g;
        f16x8 a;
        if (valid) {
            a = *(const f16x8*)(ap + k0);
        } else {
            #pragma unroll
            for (int e = 0; e < 8; ++e) a[e] = (_Float16)0.f;
        }
        #pragma unroll
        for (int nt = 0; nt < 8; ++nt) {
            f16x8 b = *(const f16x8*)&ldsW[((nt * 4 + kb) * 64 + lane) * 8];
            acc[nt] = __builtin_amdgcn_mfma_f32_16x16x32_f16(a, b, acc[nt], 0, 0, 0);
        }
    }

    #pragma unroll
    for (int reg = 0; reg < 4; ++reg) {
        const int c = brow + 4 * g + reg;
        if (c >= NC_) continue;
        const bool has = start[c + 1] > start[c];
        #pragma unroll
        for (int nt = 0; nt < 8; ++nt) {
            const int col = nt * 16 + q;
            const float hc = H_c[(size_t)c * DIM + col];
            float o = has ? 0.5f * (acc[nt][reg] + b_g[col]) + 0.5f * hc : hc;
            out[(size_t)c * DIM + col] = o;
        }
    }
}

extern "C" void kernel_launch(void* const* d_in, const int* in_sizes, int n_in,
                              void* d_out, int out_size, void* d_ws, size_t ws_size,
                              hipStream_t stream) {
    const float* H_e    = (const float*)d_in[0];
    const float* H_c    = (const float*)d_in[1];
    const float* ts     = (const float*)d_in[2];
    const float* W_e    = (const float*)d_in[3];
    const float* be_lin = (const float*)d_in[4];
    const float* b_e    = (const float*)d_in[5];
    const float* W_c    = (const float*)d_in[6];
    const float* bc_lin = (const float*)d_in[7];
    const float* b_c    = (const float*)d_in[8];
    const float* W_t    = (const float*)d_in[9];
    const float* b_t    = (const float*)d_in[10];
    const float* W_g    = (const float*)d_in[11];
    const float* b_g    = (const float*)d_in[12];
    const float* omega  = (const float*)d_in[13];
    const float* W_t2v  = (const float*)d_in[14];
    const float* b_t2v  = (const float*)d_in[15];
    const int* edge_ids = (const int*)d_in[16];
    const int* seg_ids  = (const int*)d_in[17];
    float* out = (float*)d_out;

    char* w = (char*)d_ws;
    _Float16* u16  = (_Float16*)w; w += (size_t)NE_ * DIM * sizeof(_Float16);
    _Float16* He16 = (_Float16*)w; w += (size_t)NE_ * DIM * sizeof(_Float16);
    _Float16* pc16 = (_Float16*)w; w += (size_t)NC_ * DIM * sizeof(_Float16);  // pc -> v, in place
    int* start  = (int*)w;    w += (((size_t)(NC_ + 1) * sizeof(int)) + 255) & ~(size_t)255;
    float* b_tt = (float*)w;  w += 1024;   // DIM floats = 512 B + pad (R5 fix)
    _Float16* packWe  = (_Float16*)w; w += 16384 * sizeof(_Float16);
    _Float16* packWtt = (_Float16*)w; w += 16384 * sizeof(_Float16);
    _Float16* packWc  = (_Float16*)w; w += 16384 * sizeof(_Float16);
    _Float16* packWg  = (_Float16*)w; w += 16384 * sizeof(_Float16);
    if ((size_t)(w - (char*)d_ws) > ws_size) return;  // insufficient scratch

    k_prep<<<dim3(33 + NSTART), dim3(256), 0, stream>>>(
        W_e, W_c, W_g, W_t2v, W_t, b_t2v, b_t, seg_ids,
        packWe, packWc, packWg, packWtt, b_tt, start);
    k_main<<<dim3(NTILE_E + NTILE_C), dim3(256), 0, stream>>>(
        H_e, ts, packWe, packWtt, packWc, be_lin, b_e, b_tt, bc_lin, b_c,
        omega, H_c, u16, He16, pc16);
    k_seg<<<dim3((NC_ + 3) / 4), dim3(256), 0, stream>>>(u16, pc16, He16, edge_ids, start);
    k_out<<<dim3((NC_ + 63) / 64), dim3(256), 0, stream>>>(pc16, packWg, b_g, H_c, start, out);
}

// Round 15
// 133.674 us; speedup vs baseline: 1.1934x; 1.1934x over previous
//
#include <hip/hip_runtime.h>
#include <math.h>

#define DIM   128
#define NC_   50000
#define NE_   100000
#define T_    800000
#define NTILE_E ((NE_ + 63) / 64)   // 1563
#define NTILE_C ((NC_ + 63) / 64)   // 782
#define NSTART  ((T_ + 1 + 255) / 256)

typedef __attribute__((ext_vector_type(8))) _Float16 f16x8;
typedef __attribute__((ext_vector_type(2))) _Float16 f16x2;
typedef __attribute__((ext_vector_type(4))) float f32x4;

__device__ __forceinline__ float sigmoidf_(float x) {
    return 1.f / (1.f + __expf(-x));
}

__device__ __forceinline__ float dot2f(f16x2 a, f16x2 b, float c) {
#if defined(__has_builtin) && __has_builtin(__builtin_amdgcn_fdot2)
    return __builtin_amdgcn_fdot2(a, b, c, false);
#else
    return c + (float)a[0] * (float)b[0] + (float)a[1] * (float)b[1];
#endif
}

// ---- K0: W_tt = W_t2v @ W_t ; b_tt = b_t2v @ W_t + b_t
__global__ __launch_bounds__(128)
void k_combine(const float* __restrict__ W_t2v, const float* __restrict__ W_t,
               const float* __restrict__ b_t2v, const float* __restrict__ b_t,
               float* __restrict__ W_tt, float* __restrict__ b_tt) {
    const int i = blockIdx.x, j = threadIdx.x;
    float acc = 0.f;
    if (i < DIM) {
        for (int k = 0; k < DIM; ++k) acc = fmaf(W_t2v[i*DIM+k], W_t[k*DIM+j], acc);
        W_tt[i*DIM+j] = acc;
    } else {
        for (int k = 0; k < DIM; ++k) acc = fmaf(b_t2v[k], W_t[k*DIM+j], acc);
        b_tt[j] = acc + b_t[j];
    }
}

// ---- pack 128x128 f32 W into f16 B-fragment layout (single plane, 32KB).
// frag elem (nt,kb,lane,e): k = kb*32 + 8*(lane>>4)+e ; n = nt*16 + (lane&15)
__global__ __launch_bounds__(64)
void k_pack(const float* __restrict__ s0, const float* __restrict__ s1,
            const float* __restrict__ s2, const float* __restrict__ s3,
            _Float16* __restrict__ d0, _Float16* __restrict__ d1,
            _Float16* __restrict__ d2, _Float16* __restrict__ d3) {
    const float* srcs[4] = {s0, s1, s2, s3};
    _Float16* dsts[4] = {d0, d1, d2, d3};
    const float* src = srcs[blockIdx.y];
    _Float16* dst = dsts[blockIdx.y];
    const int b = blockIdx.x;          // 0..31
    const int nt = b >> 2, kb = b & 3;
    const int lane = threadIdx.x;
    const int n  = nt * 16 + (lane & 15);
    const int k0 = kb * 32 + 8 * (lane >> 4);
    const size_t off = ((size_t)(nt * 4 + kb) * 64 + lane) * 8;
    #pragma unroll
    for (int e = 0; e < 8; ++e)
        dst[off + e] = (_Float16)src[(size_t)(k0 + e) * DIM + n];
}

__device__ __forceinline__ void split8h(const float* xs, f16x8* hi, f16x8* lo) {
    #pragma unroll
    for (int e = 0; e < 8; ++e) {
        _Float16 h = (_Float16)xs[e];
        (*hi)[e] = h;
        (*lo)[e] = (_Float16)(xs[e] - (float)h);
    }
}

__device__ __forceinline__ void stage_lds(_Float16* lds, const _Float16* __restrict__ g) {
    const int tid = threadIdx.x;
    #pragma unroll
    for (int i = 0; i < 8; ++i)
        ((uint4*)lds)[tid + i * 256] = ((const uint4*)g)[tid + i * 256];
}

__device__ __forceinline__ void mfma2(f16x8 ahi, f16x8 alo, const _Float16* lds_bp,
                                      f32x4* acc) {
    f16x8 b = *(const f16x8*)lds_bp;
    *acc = __builtin_amdgcn_mfma_f32_16x16x32_f16(ahi, b, *acc, 0, 0, 0);
    *acc = __builtin_amdgcn_mfma_f32_16x16x32_f16(alo, b, *acc, 0, 0, 0);
}

#define TSTRIDE 136   // padded f16 row stride for the LDS transpose buffer

// ---- K1 (merged): blocks [0,NTILE_E) edge path; [NTILE_E, NTILE_E+NTILE_C) code
// path; [NTILE_E+NTILE_C, +NSTART) segment-start scan (start[] consumed by k_seg).
__global__ __launch_bounds__(256)
void k_main(const float* __restrict__ H_e, const float* __restrict__ ts,
            const _Float16* __restrict__ packWe, const _Float16* __restrict__ packWtt,
            const _Float16* __restrict__ packWc,
            const float* __restrict__ be_lin, const float* __restrict__ b_e,
            const float* __restrict__ b_tt,
            const float* __restrict__ bc_lin, const float* __restrict__ b_c,
            const float* __restrict__ omega, const float* __restrict__ H_c,
            const int* __restrict__ seg,
            _Float16* __restrict__ u16, _Float16* __restrict__ He16,
            _Float16* __restrict__ pc16, int* __restrict__ start) {
    __shared__ __align__(16) _Float16 ldsW[16384];   // 32KB; reused as transpose buf
    const int tid  = threadIdx.x;
    const int lane = tid & 63;
    const int q    = lane & 15, g = lane >> 4;
    const int wv   = tid >> 6;

    if (blockIdx.x >= NTILE_E + NTILE_C) {
        // ================= starts path (no LDS/MFMA; exits fast) =================
        const int t = (blockIdx.x - NTILE_E - NTILE_C) * 256 + tid;
        if (t > T_) return;
        if (t < T_) {
            int s  = seg[t];
            int sp = (t > 0) ? seg[t - 1] : -1;
            for (int c = sp + 1; c <= s; ++c) start[c] = t;
        } else {
            int sp = seg[T_ - 1];
            for (int c = sp + 1; c <= NC_; ++c) start[c] = T_;
        }
        return;
    }

    if (blockIdx.x < NTILE_E) {
        // ================= edge path =================
        const int tile = blockIdx.x;
        const int brow = tile * 64 + wv * 16;
        const int arow = brow + q;
        const bool valid = arow < NE_;
        const float* ap = H_e + (size_t)(valid ? arow : 0) * DIM;
        const float te  = valid ? ts[arow] : 0.f;

        stage_lds(ldsW, packWe);

        f32x4 accU[8], accG[8];
        #pragma unroll
        for (int i = 0; i < 8; ++i) {
            accU[i] = (f32x4){0.f, 0.f, 0.f, 0.f};
            accG[i] = (f32x4){0.f, 0.f, 0.f, 0.f};
        }
        __syncthreads();

        // ---- GEMM U: H_e row @ We
        #pragma unroll
        for (int kb = 0; kb < 4; ++kb) {
            const int k0 = kb * 32 + 8 * g;
            float xs[8];
            if (valid) {
                float4 x0 = *(const float4*)(ap + k0);
                float4 x1 = *(const float4*)(ap + k0 + 4);
                xs[0]=x0.x; xs[1]=x0.y; xs[2]=x0.z; xs[3]=x0.w;
                xs[4]=x1.x; xs[5]=x1.y; xs[6]=x1.z; xs[7]=x1.w;
            } else {
                #pragma unroll
                for (int e = 0; e < 8; ++e) xs[e] = 0.f;
            }
            f16x8 ahi, alo;
            split8h(xs, &ahi, &alo);
            if (valid) *(f16x8*)&He16[(size_t)arow * DIM + k0] = ahi;  // 16B coalesced
            #pragma unroll
            for (int nt = 0; nt < 8; ++nt)
                mfma2(ahi, alo, &ldsW[((nt * 4 + kb) * 64 + lane) * 8], &accU[nt]);
        }

        __syncthreads();
        stage_lds(ldsW, packWtt);
        __syncthreads();

        // ---- GEMM G: trig(e) @ Wtt
        #pragma unroll
        for (int kb = 0; kb < 4; ++kb) {
            const int k0 = kb * 32 + 8 * g;
            float ys[8];
            #pragma unroll
            for (int e = 0; e < 8; ++e) {
                const int k = k0 + e;
                float x = te * omega[k & 63];
                float s, c;
                __sincosf(x, &s, &c);
                ys[e] = (k < 64) ? c : s;
            }
            f16x8 thi, tlo;
            split8h(ys, &thi, &tlo);
            #pragma unroll
            for (int nt = 0; nt < 8; ++nt)
                mfma2(thi, tlo, &ldsW[((nt * 4 + kb) * 64 + lane) * 8], &accG[nt]);
        }

        // ---- epilogue: u -> LDS transpose -> coalesced 64B stores
        __syncthreads();    // all Wtt reads done; ldsW reusable
        #pragma unroll
        for (int nt = 0; nt < 8; ++nt) {
            const int col = nt * 16 + q;
            const float bu = be_lin[col] + b_e[col];
            const float bg = b_tt[col];
            #pragma unroll
            for (int reg = 0; reg < 4; ++reg) {
                float val = (accU[nt][reg] + bu) * sigmoidf_(accG[nt][reg] + bg);
                ldsW[(wv * 16 + 4 * g + reg) * TSTRIDE + col] = (_Float16)val;
            }
        }
        __syncthreads();
        {
            const int row = tid >> 2;           // 0..63
            const int c0  = (tid & 3) * 32;     // 0,32,64,96
            const int er  = tile * 64 + row;
            if (er < NE_) {
                const _Float16* sp = &ldsW[row * TSTRIDE + c0];
                uint4* dst = (uint4*)&u16[(size_t)er * DIM + c0];
                dst[0] = *(const uint4*)(sp + 0);
                dst[1] = *(const uint4*)(sp + 8);
                dst[2] = *(const uint4*)(sp + 16);
                dst[3] = *(const uint4*)(sp + 24);
            }
        }
    } else {
        // ================= code path =================
        const int tile = blockIdx.x - NTILE_E;
        const int brow = tile * 64 + wv * 16;
        const int arow = brow + q;
        const bool valid = arow < NC_;
        const float* ap = H_c + (size_t)(valid ? arow : 0) * DIM;

        stage_lds(ldsW, packWc);

        f32x4 acc[8];
        #pragma unroll
        for (int i = 0; i < 8; ++i) acc[i] = (f32x4){0.f, 0.f, 0.f, 0.f};
        __syncthreads();

        #pragma unroll
        for (int kb = 0; kb < 4; ++kb) {
            const int k0 = kb * 32 + 8 * g;
            float xs[8];
            if (valid) {
                float4 x0 = *(const float4*)(ap + k0);
                float4 x1 = *(const float4*)(ap + k0 + 4);
                xs[0]=x0.x; xs[1]=x0.y; xs[2]=x0.z; xs[3]=x0.w;
                xs[4]=x1.x; xs[5]=x1.y; xs[6]=x1.z; xs[7]=x1.w;
            } else {
                #pragma unroll
                for (int e = 0; e < 8; ++e) xs[e] = 0.f;
            }
            f16x8 ahi, alo;
            split8h(xs, &ahi, &alo);
            #pragma unroll
            for (int nt = 0; nt < 8; ++nt)
                mfma2(ahi, alo, &ldsW[((nt * 4 + kb) * 64 + lane) * 8], &acc[nt]);
        }

        __syncthreads();    // all Wc reads done; ldsW reusable
        #pragma unroll
        for (int nt = 0; nt < 8; ++nt) {
            const int col = nt * 16 + q;
            const float bc = bc_lin[col] + b_c[col];
            #pragma unroll
            for (int reg = 0; reg < 4; ++reg)
                ldsW[(wv * 16 + 4 * g + reg) * TSTRIDE + col] = (_Float16)(acc[nt][reg] + bc);
        }
        __syncthreads();
        {
            const int row = tid >> 2;
            const int c0  = (tid & 3) * 32;
            const int cr  = tile * 64 + row;
            if (cr < NC_) {
                const _Float16* sp = &ldsW[row * TSTRIDE + c0];
                uint4* dst = (uint4*)&pc16[(size_t)cr * DIM + c0];
                dst[0] = *(const uint4*)(sp + 0);
                dst[1] = *(const uint4*)(sp + 8);
                dst[2] = *(const uint4*)(sp + 16);
                dst[3] = *(const uint4*)(sp + 24);
            }
        }
    }
}

// ---- K3: fused segment softmax + aggregation (f16 gathers, fdot2). R10-proven.
__global__ __launch_bounds__(256)
void k_seg(const _Float16* __restrict__ u16, _Float16* __restrict__ pc16,
           const _Float16* __restrict__ He16, const int* __restrict__ edge_ids,
           const int* __restrict__ start) {
    const int lane = threadIdx.x & 63;
    const int c = blockIdx.x * 4 + (threadIdx.x >> 6);
    if (c >= NC_) return;
    const int lo = start[c], hi = start[c + 1];
    const int g = lane >> 3;     // group 0..7
    const int q = lane & 7;      // lane in group
    const int j0 = q * 16;       // 16 dims owned by this lane

    union { uint4 r[2]; f16x2 h2[8]; } pcu;
    pcu.r[0] = *(const uint4*)&pc16[(size_t)c * DIM + j0];
    pcu.r[1] = *(const uint4*)&pc16[(size_t)c * DIM + j0 + 8];

    float M = -INFINITY, S = 0.f;
    float acc[16];
    #pragma unroll
    for (int i = 0; i < 16; ++i) acc[i] = 0.f;

    for (int base = lo; base < hi; base += 64) {
        const int n = min(64, hi - base);
        const int eid = (base + lane < hi) ? edge_ids[base + lane] : 0;
        const int niter = (n + 7) >> 3;
        float msc = -INFINITY;

        for (int jj = 0; jj < niter; ++jj) {
            const int s = 8 * jj + g;
            const int e = __shfl(eid, s);
            float p = 0.f;
            if (s < n) {
                union { uint4 r[2]; f16x2 h2[8]; } uu;
                const _Float16* up = &u16[(size_t)e * DIM + j0];
                uu.r[0] = *(const uint4*)up;
                uu.r[1] = *(const uint4*)(up + 8);
                #pragma unroll
                for (int i = 0; i < 8; ++i) p = dot2f(uu.h2[i], pcu.h2[i], p);
            }
            p += __shfl_xor(p, 1);
            p += __shfl_xor(p, 2);
            p += __shfl_xor(p, 4);
            if (q == jj && s < n) msc = p;
        }

        float cm = msc;
        #pragma unroll
        for (int off = 32; off; off >>= 1) cm = fmaxf(cm, __shfl_xor(cm, off));
        const float nM = fmaxf(M, cm);
        const float scale = __expf(M - nM);
        const float pi = __expf(msc - nM);
        float ss = pi;
        #pragma unroll
        for (int off = 32; off; off >>= 1) ss += __shfl_xor(ss, off);
        S = S * scale + ss;
        #pragma unroll
        for (int i = 0; i < 16; ++i) acc[i] *= scale;
        M = nM;

        for (int jj = 0; jj < niter; ++jj) {
            const int s = 8 * jj + g;
            const int e = __shfl(eid, s);
            const float p = __shfl(pi, 8 * g + jj);
            if (s < n) {
                union { uint4 r[2]; f16x8 h8[2]; } hh;
                const _Float16* hp = &He16[(size_t)e * DIM + j0];
                hh.r[0] = *(const uint4*)hp;
                hh.r[1] = *(const uint4*)(hp + 8);
                #pragma unroll
                for (int i = 0; i < 8; ++i) {
                    acc[i]     = fmaf(p, (float)hh.h8[0][i], acc[i]);
                    acc[8 + i] = fmaf(p, (float)hh.h8[1][i], acc[8 + i]);
                }
            }
        }
    }

    #pragma unroll
    for (int off = 8; off <= 32; off <<= 1) {
        #pragma unroll
        for (int i = 0; i < 16; ++i) acc[i] += __shfl_xor(acc[i], off);
    }

    if (g == 0) {
        const float inv = (hi > lo) ? 1.f / fmaxf(S, 1e-30f) : 0.f;
        union { uint4 r[2]; _Float16 h[16]; } o;
        #pragma unroll
        for (int i = 0; i < 16; ++i) o.h[i] = (_Float16)(acc[i] * inv);
        *(uint4*)&pc16[(size_t)c * DIM + j0]     = o.r[0];
        *(uint4*)&pc16[(size_t)c * DIM + j0 + 8] = o.r[1];
    }
}

// ---- K5: out[c] = has_edge ? 0.5*(v16@W_g + b_g) + 0.5*H_c : H_c
__global__ __launch_bounds__(256)
void k_out(const _Float16* __restrict__ v16, const _Float16* __restrict__ packWg,
           const float* __restrict__ b_g, const float* __restrict__ H_c,
           const int* __restrict__ start, float* __restrict__ out) {
    __shared__ __align__(16) _Float16 ldsW[16384];
    const int tid  = threadIdx.x;
    const int lane = tid & 63;
    const int q    = lane & 15, g = lane >> 4;
    const int brow = blockIdx.x * 64 + (tid >> 6) * 16;
    const int arow = brow + q;
    const bool valid = arow < NC_;
    const _Float16* ap = v16 + (size_t)(valid ? arow : 0) * DIM;

    stage_lds(ldsW, packWg);

    f32x4 acc[8];
    #pragma unroll
    for (int i = 0; i < 8; ++i) acc[i] = (f32x4){0.f, 0.f, 0.f, 0.f};
    __syncthreads();

    #pragma unroll
    for (int kb = 0; kb < 4; ++kb) {
        const int k0 = kb * 32 + 8 * g;
        f16x8 a;
        if (valid) {
            a = *(const f16x8*)(ap + k0);
        } else {
            #pragma unroll
            for (int e = 0; e < 8; ++e) a[e] = (_Float16)0.f;
        }
        #pragma unroll
        for (int nt = 0; nt < 8; ++nt) {
            f16x8 b = *(const f16x8*)&ldsW[((nt * 4 + kb) * 64 + lane) * 8];
            acc[nt] = __builtin_amdgcn_mfma_f32_16x16x32_f16(a, b, acc[nt], 0, 0, 0);
        }
    }

    #pragma unroll
    for (int reg = 0; reg < 4; ++reg) {
        const int c = brow + 4 * g + reg;
        if (c >= NC_) continue;
        const bool has = start[c + 1] > start[c];
        #pragma unroll
        for (int nt = 0; nt < 8; ++nt) {
            const int col = nt * 16 + q;
            const float hc = H_c[(size_t)c * DIM + col];
            float o = has ? 0.5f * (acc[nt][reg] + b_g[col]) + 0.5f * hc : hc;
            out[(size_t)c * DIM + col] = o;
        }
    }
}

extern "C" void kernel_launch(void* const* d_in, const int* in_sizes, int n_in,
                              void* d_out, int out_size, void* d_ws, size_t ws_size,
                              hipStream_t stream) {
    const float* H_e    = (const float*)d_in[0];
    const float* H_c    = (const float*)d_in[1];
    const float* ts     = (const float*)d_in[2];
    const float* W_e    = (const float*)d_in[3];
    const float* be_lin = (const float*)d_in[4];
    const float* b_e    = (const float*)d_in[5];
    const float* W_c    = (const float*)d_in[6];
    const float* bc_lin = (const float*)d_in[7];
    const float* b_c    = (const float*)d_in[8];
    const float* W_t    = (const float*)d_in[9];
    const float* b_t    = (const float*)d_in[10];
    const float* W_g    = (const float*)d_in[11];
    const float* b_g    = (const float*)d_in[12];
    const float* omega  = (const float*)d_in[13];
    const float* W_t2v  = (const float*)d_in[14];
    const float* b_t2v  = (const float*)d_in[15];
    const int* edge_ids = (const int*)d_in[16];
    const int* seg_ids  = (const int*)d_in[17];
    float* out = (float*)d_out;

    char* w = (char*)d_ws;
    _Float16* u16  = (_Float16*)w; w += (size_t)NE_ * DIM * sizeof(_Float16);
    _Float16* He16 = (_Float16*)w; w += (size_t)NE_ * DIM * sizeof(_Float16);
    _Float16* pc16 = (_Float16*)w; w += (size_t)NC_ * DIM * sizeof(_Float16);  // pc -> v, in place
    int* start  = (int*)w;    w += (((size_t)(NC_ + 1) * sizeof(int)) + 255) & ~(size_t)255;
    float* W_tt = (float*)w;  w += (size_t)DIM * DIM * sizeof(float);
    float* b_tt = (float*)w;  w += 1024;   // DIM floats = 512 B + pad (R5 fix)
    _Float16* packWe  = (_Float16*)w; w += 16384 * sizeof(_Float16);
    _Float16* packWtt = (_Float16*)w; w += 16384 * sizeof(_Float16);
    _Float16* packWc  = (_Float16*)w; w += 16384 * sizeof(_Float16);
    _Float16* packWg  = (_Float16*)w; w += 16384 * sizeof(_Float16);
    if ((size_t)(w - (char*)d_ws) > ws_size) return;  // insufficient scratch

    k_combine<<<dim3(DIM + 1), dim3(128), 0, stream>>>(W_t2v, W_t, b_t2v, b_t, W_tt, b_tt);
    k_pack<<<dim3(32, 4), dim3(64), 0, stream>>>(W_e, W_tt, W_c, W_g,
                                                 packWe, packWtt, packWc, packWg);
    k_main<<<dim3(NTILE_E + NTILE_C + NSTART), dim3(256), 0, stream>>>(
        H_e, ts, packWe, packWtt, packWc, be_lin, b_e, b_tt, bc_lin, b_c,
        omega, H_c, seg_ids, u16, He16, pc16, start);
    k_seg<<<dim3((NC_ + 3) / 4), dim3(256), 0, stream>>>(u16, pc16, He16, edge_ids, start);
    k_out<<<dim3((NC_ + 63) / 64), dim3(256), 0, stream>>>(pc16, packWg, b_g, H_c, start, out);
}